// Round 1
// baseline (1389.401 us; speedup 1.0000x reference)
//
#include <hip/hip_runtime.h>
#include <hip/hip_bf16.h>
#include <stdint.h>
#include <stddef.h>

#define E_ 8
#define C_ 4096
#define H_ 1024
#define I_ 4096

typedef short s16;
typedef __attribute__((ext_vector_type(8))) short short8;   // 8 bf16 (4 VGPRs)
typedef __attribute__((ext_vector_type(4))) float f32x4;    // MFMA C/D frag
typedef __attribute__((ext_vector_type(4))) float float4v;

__device__ __forceinline__ s16 f2bf(float f) {
  union { __hip_bfloat16 h; s16 s; } u;
  u.h = __float2bfloat16(f);
  return u.s;
}

// async global->LDS, 16B per lane. LDS dest must be wave-uniform base;
// HW writes lane l at base + l*16. Global src address is per-lane.
__device__ __forceinline__ void gload16(const void* gsrc, void* ldst) {
  __builtin_amdgcn_global_load_lds(
      (const __attribute__((address_space(1))) void*)gsrc,
      (__attribute__((address_space(3))) void*)ldst,
      16, 0, 0);
}

// ---------------------------------------------------------------------------
// prep: blockIdx.z = 0: convert x (fp32 C_*H_ -> bf16)
//                    1: Wg (H_ x I_ fp32) -> WgT (I_ x H_ bf16)
//                    2: Wu -> WuT
//                    3: Wd (I_ x H_ fp32) -> WdT (H_ x I_ bf16)
// grid: (1024, 1, 4), 256 threads
// ---------------------------------------------------------------------------
__global__ __launch_bounds__(256) void prep_kernel(
    const float* __restrict__ x, const float* __restrict__ Wg,
    const float* __restrict__ Wu, const float* __restrict__ Wd,
    s16* __restrict__ xb, s16* __restrict__ WgT,
    s16* __restrict__ WuT, s16* __restrict__ WdT)
{
  __shared__ float tile[64][65];   // +1 pad: conflict-free transposed reads
  const int t = threadIdx.x;
  const int z = blockIdx.z;

  if (z == 0) {
    // straight convert, 16 elements/thread, vectorized
    size_t base = ((size_t)blockIdx.x * 256 + t) * 16;
    for (int j = 0; j < 16; j += 8) {
      float4v v0 = *(const float4v*)(x + base + j);
      float4v v1 = *(const float4v*)(x + base + j + 4);
      s16 o[8];
      o[0] = f2bf(v0[0]); o[1] = f2bf(v0[1]); o[2] = f2bf(v0[2]); o[3] = f2bf(v0[3]);
      o[4] = f2bf(v1[0]); o[5] = f2bf(v1[1]); o[6] = f2bf(v1[2]); o[7] = f2bf(v1[3]);
      *(short8*)(xb + base + j) = *(short8*)o;
    }
    return;
  }

  const float* src; s16* dst; int R, Cc;
  if (z == 1)      { src = Wg; dst = WgT; R = H_; Cc = I_; }
  else if (z == 2) { src = Wu; dst = WuT; R = H_; Cc = I_; }
  else             { src = Wd; dst = WdT; R = I_; Cc = H_; }

  const int tpr  = Cc >> 6;                   // tiles per src row-band
  const int trow = blockIdx.x / tpr;
  const int tcol = blockIdx.x % tpr;

  // load 64x64 fp32 tile, coalesced
  const int c = t & 63, rq = t >> 6;
  for (int i = 0; i < 16; ++i) {
    int r = rq * 16 + i;
    tile[r][c] = src[(size_t)(trow * 64 + r) * Cc + tcol * 64 + c];
  }
  __syncthreads();

  // write transposed as bf16, 16 elems (32B, two b128 stores) per thread
  const int ro = t >> 2, cb = (t & 3) * 16;
  s16 o[16];
  for (int j = 0; j < 16; ++j) o[j] = f2bf(tile[cb + j][ro]);
  s16* op = dst + (size_t)(tcol * 64 + ro) * R + trow * 64 + cb;
  *(short8*)op       = *(short8*)&o[0];
  *(short8*)(op + 8) = *(short8*)&o[8];
}

// ---------------------------------------------------------------------------
// gemm_gateup: h = silu(x@Wg) * (x@Wu), one expert.
// A  = xb  [C_][H_] bf16 row-major (K contiguous)
// Bt = W*T [I_][H_] bf16 (N x K, K contiguous)
// out Hout [C_][I_] bf16
// BM=BN=128, BK=64; 256 thr = 4 waves (2x2), 64x64 out per wave per matrix.
// ---------------------------------------------------------------------------
__global__ __launch_bounds__(256, 2) void gemm_gateup(
    const s16* __restrict__ A,
    const s16* __restrict__ BgT,
    const s16* __restrict__ BuT,
    s16* __restrict__ Hout)
{
  constexpr int K = H_;   // 1024
  constexpr int N = I_;   // 4096
  __shared__ s16 sA[128 * 64], sBg[128 * 64], sBu[128 * 64];   // 48 KiB

  const int tid  = threadIdx.x;
  const int wave = tid >> 6, lane = tid & 63;
  const int rowA0 = blockIdx.y * 128;     // M tile
  const int rowB0 = blockIdx.x * 128;     // N tile
  const int wm = (wave >> 1) * 64, wn = (wave & 1) * 64;

  f32x4 accG[4][4], accU[4][4];
  for (int m = 0; m < 4; ++m)
    for (int n = 0; n < 4; ++n) {
      accG[m][n] = (f32x4){0.f, 0.f, 0.f, 0.f};
      accU[m][n] = (f32x4){0.f, 0.f, 0.f, 0.f};
    }

  const int srow = lane >> 3, scol = (lane & 7) * 8;   // staging lane map
  const int lr = lane & 15, lkb = (lane >> 4) * 8;     // fragment lane map

  for (int kt = 0; kt < K / 64; ++kt) {
    const int k0 = kt * 64;
    // stage A, Bg, Bu tiles: each wave 4 chunks/tile, 1KiB per gload16
    for (int i = 0; i < 4; ++i) {
      const int chunk = wave * 4 + i;          // rows 8*chunk .. 8*chunk+7
      const int r = chunk * 8 + srow;
      gload16(A   + (size_t)(rowA0 + r) * K + k0 + scol, &sA [chunk * 512]);
      gload16(BgT + (size_t)(rowB0 + r) * K + k0 + scol, &sBg[chunk * 512]);
      gload16(BuT + (size_t)(rowB0 + r) * K + k0 + scol, &sBu[chunk * 512]);
    }
    __syncthreads();   // compiler drains vmcnt before s_barrier

    for (int kk = 0; kk < 2; ++kk) {
      short8 a[4], bg[4], bu[4];
      const int lk = kk * 32 + lkb;
      for (int m = 0; m < 4; ++m)
        a[m] = *(const short8*)&sA[(wm + m * 16 + lr) * 64 + lk];
      for (int n = 0; n < 4; ++n) {
        bg[n] = *(const short8*)&sBg[(wn + n * 16 + lr) * 64 + lk];
        bu[n] = *(const short8*)&sBu[(wn + n * 16 + lr) * 64 + lk];
      }
      for (int m = 0; m < 4; ++m)
        for (int n = 0; n < 4; ++n) {
          accG[m][n] = __builtin_amdgcn_mfma_f32_16x16x32_bf16(a[m], bg[n], accG[m][n], 0, 0, 0);
          accU[m][n] = __builtin_amdgcn_mfma_f32_16x16x32_bf16(a[m], bu[n], accU[m][n], 0, 0, 0);
        }
    }
    __syncthreads();
  }

  // epilogue: silu(g)*u -> bf16.  C/D map: col = lane&15, row = (lane>>4)*4 + j
  const int lq = (lane >> 4) * 4;
  for (int m = 0; m < 4; ++m)
    for (int n = 0; n < 4; ++n) {
      const int row = rowA0 + wm + m * 16 + lq;
      const int col = rowB0 + wn + n * 16 + lr;
      s16* hp = Hout + (size_t)row * N + col;
      for (int j = 0; j < 4; ++j) {
        float g = accG[m][n][j], u = accU[m][n][j];
        float sg = 1.0f / (1.0f + __expf(-g));
        hp[(size_t)j * N] = f2bf(g * sg * u);
      }
    }
}

// ---------------------------------------------------------------------------
// gemm_down: out = h @ Wd, one expert.
// A  = h   [C_][I_] bf16, Bt = WdT [H_][I_] bf16, out fp32 [C_][H_]
// ---------------------------------------------------------------------------
__global__ __launch_bounds__(256, 2) void gemm_down(
    const s16* __restrict__ A,
    const s16* __restrict__ BT,
    float* __restrict__ Out)
{
  constexpr int K = I_;   // 4096
  constexpr int N = H_;   // 1024
  __shared__ s16 sA[128 * 64], sB[128 * 64];   // 32 KiB

  const int tid  = threadIdx.x;
  const int wave = tid >> 6, lane = tid & 63;
  const int rowA0 = blockIdx.y * 128;
  const int rowB0 = blockIdx.x * 128;
  const int wm = (wave >> 1) * 64, wn = (wave & 1) * 64;

  f32x4 acc[4][4];
  for (int m = 0; m < 4; ++m)
    for (int n = 0; n < 4; ++n) acc[m][n] = (f32x4){0.f, 0.f, 0.f, 0.f};

  const int srow = lane >> 3, scol = (lane & 7) * 8;
  const int lr = lane & 15, lkb = (lane >> 4) * 8;

  for (int kt = 0; kt < K / 64; ++kt) {
    const int k0 = kt * 64;
    for (int i = 0; i < 4; ++i) {
      const int chunk = wave * 4 + i;
      const int r = chunk * 8 + srow;
      gload16(A  + (size_t)(rowA0 + r) * K + k0 + scol, &sA[chunk * 512]);
      gload16(BT + (size_t)(rowB0 + r) * K + k0 + scol, &sB[chunk * 512]);
    }
    __syncthreads();

    for (int kk = 0; kk < 2; ++kk) {
      short8 a[4], b[4];
      const int lk = kk * 32 + lkb;
      for (int m = 0; m < 4; ++m)
        a[m] = *(const short8*)&sA[(wm + m * 16 + lr) * 64 + lk];
      for (int n = 0; n < 4; ++n)
        b[n] = *(const short8*)&sB[(wn + n * 16 + lr) * 64 + lk];
      for (int m = 0; m < 4; ++m)
        for (int n = 0; n < 4; ++n)
          acc[m][n] = __builtin_amdgcn_mfma_f32_16x16x32_bf16(a[m], b[n], acc[m][n], 0, 0, 0);
    }
    __syncthreads();
  }

  const int lq = (lane >> 4) * 4;
  for (int m = 0; m < 4; ++m)
    for (int n = 0; n < 4; ++n) {
      const int row = rowA0 + wm + m * 16 + lq;
      const int col = rowB0 + wn + n * 16 + lr;
      float* op = Out + (size_t)row * N + col;
      for (int j = 0; j < 4; ++j)
        op[(size_t)j * N] = acc[m][n][j];
    }
}

// ---------------------------------------------------------------------------
extern "C" void kernel_launch(void* const* d_in, const int* in_sizes, int n_in,
                              void* d_out, int out_size, void* d_ws, size_t ws_size,
                              hipStream_t stream) {
  const float* x  = (const float*)d_in[0];
  const float* Wg = (const float*)d_in[1];
  const float* Wu = (const float*)d_in[2];
  const float* Wd = (const float*)d_in[3];
  float* out = (float*)d_out;

  // workspace layout (per-expert reuse, 67.1 MB total):
  s16* xb  = (s16*)d_ws;                     // C_*H_
  s16* WgT = xb  + (size_t)C_ * H_;          // I_*H_
  s16* WuT = WgT + (size_t)I_ * H_;          // I_*H_
  s16* WdT = WuT + (size_t)I_ * H_;          // H_*I_
  s16* hbf = WdT + (size_t)H_ * I_;          // C_*I_

  for (int e = 0; e < E_; ++e) {
    const float* xe  = x  + (size_t)e * C_ * H_;
    const float* Wge = Wg + (size_t)e * H_ * I_;
    const float* Wue = Wu + (size_t)e * H_ * I_;
    const float* Wde = Wd + (size_t)e * I_ * H_;

    prep_kernel<<<dim3(1024, 1, 4), 256, 0, stream>>>(
        xe, Wge, Wue, Wde, xb, WgT, WuT, WdT);
    gemm_gateup<<<dim3(I_ / 128, C_ / 128), 256, 0, stream>>>(
        xb, WgT, WuT, hbf);
    gemm_down<<<dim3(H_ / 128, C_ / 128), 256, 0, stream>>>(
        hbf, WdT, out + (size_t)e * C_ * H_);
  }
}

// Round 2
// 1154.625 us; speedup vs baseline: 1.2033x; 1.2033x over previous
//
#include <hip/hip_runtime.h>
#include <hip/hip_bf16.h>
#include <stdint.h>
#include <stddef.h>

#define E_ 8
#define C_ 4096
#define H_ 1024
#define I_ 4096

typedef short s16;
typedef __attribute__((ext_vector_type(8))) short short8;   // 8 bf16 (4 VGPRs)
typedef __attribute__((ext_vector_type(4))) float f32x4;    // MFMA C/D frag
typedef __attribute__((ext_vector_type(4))) float float4v;

__device__ __forceinline__ s16 f2bf(float f) {
  union { __hip_bfloat16 h; s16 s; } u;
  u.h = __float2bfloat16(f);
  return u.s;
}

// async global->LDS, 16B per lane. LDS dest must be wave-uniform base;
// HW writes lane l at base + l*16. Global src address is per-lane.
__device__ __forceinline__ void gload16(const void* gsrc, void* ldst) {
  __builtin_amdgcn_global_load_lds(
      (const __attribute__((address_space(1))) void*)gsrc,
      (__attribute__((address_space(3))) void*)ldst,
      16, 0, 0);
}

// ---------------------------------------------------------------------------
// prep: expert = blockIdx.y
// blockIdx.z = 0: convert x (fp32 C_*H_ -> bf16)
//             1: Wg (H_ x I_ fp32) -> WgT (I_ x H_ bf16)
//             2: Wu -> WuT
//             3: Wd (I_ x H_ fp32) -> WdT (H_ x I_ bf16)
// grid: (1024, E, 4), 256 threads.  (fallback mode: y=1, pre-offset ptrs)
// ---------------------------------------------------------------------------
__global__ __launch_bounds__(256) void prep_kernel(
    const float* __restrict__ x, const float* __restrict__ Wg,
    const float* __restrict__ Wu, const float* __restrict__ Wd,
    s16* __restrict__ xb, s16* __restrict__ WgT,
    s16* __restrict__ WuT, s16* __restrict__ WdT)
{
  __shared__ float tile[64][65];   // +1 pad: conflict-free transposed reads
  const int t = threadIdx.x;
  const int z = blockIdx.z;
  const size_t e = blockIdx.y;
  const size_t wOff = e * (size_t)H_ * I_;   // all three weights same size

  if (z == 0) {
    // straight convert, 16 elements/thread, vectorized
    size_t base = e * (size_t)C_ * H_ + ((size_t)blockIdx.x * 256 + t) * 16;
    for (int j = 0; j < 16; j += 8) {
      float4v v0 = *(const float4v*)(x + base + j);
      float4v v1 = *(const float4v*)(x + base + j + 4);
      s16 o[8];
      o[0] = f2bf(v0[0]); o[1] = f2bf(v0[1]); o[2] = f2bf(v0[2]); o[3] = f2bf(v0[3]);
      o[4] = f2bf(v1[0]); o[5] = f2bf(v1[1]); o[6] = f2bf(v1[2]); o[7] = f2bf(v1[3]);
      *(short8*)(xb + base + j) = *(short8*)o;
    }
    return;
  }

  const float* src; s16* dst; int R, Cc;
  if (z == 1)      { src = Wg + wOff; dst = WgT + wOff; R = H_; Cc = I_; }
  else if (z == 2) { src = Wu + wOff; dst = WuT + wOff; R = H_; Cc = I_; }
  else             { src = Wd + wOff; dst = WdT + wOff; R = I_; Cc = H_; }

  const int tpr  = Cc >> 6;                   // tiles per src row-band
  const int trow = blockIdx.x / tpr;
  const int tcol = blockIdx.x % tpr;

  // load 64x64 fp32 tile, coalesced
  const int c = t & 63, rq = t >> 6;
  for (int i = 0; i < 16; ++i) {
    int r = rq * 16 + i;
    tile[r][c] = src[(size_t)(trow * 64 + r) * Cc + tcol * 64 + c];
  }
  __syncthreads();

  // write transposed as bf16, 16 elems (32B, two b128 stores) per thread
  const int ro = t >> 2, cb = (t & 3) * 16;
  s16 o[16];
  for (int j = 0; j < 16; ++j) o[j] = f2bf(tile[cb + j][ro]);
  s16* op = dst + (size_t)(tcol * 64 + ro) * R + trow * 64 + cb;
  *(short8*)op       = *(short8*)&o[0];
  *(short8*)(op + 8) = *(short8*)&o[8];
}

// ---------------------------------------------------------------------------
// gemm_gateup: h = silu(x@Wg) * (x@Wu).  expert = blockIdx.z.
// A  = xb  [e][C_][H_] bf16 row-major (K contiguous)
// Bt = W*T [e][I_][H_] bf16 (N x K, K contiguous)
// out Hout [e][C_][I_] bf16
// BM=BN=128, BK=64; 256 thr = 4 waves (2x2), 64x64 out per wave per matrix.
// ---------------------------------------------------------------------------
__global__ __launch_bounds__(256, 2) void gemm_gateup(
    const s16* __restrict__ A_,
    const s16* __restrict__ BgT_,
    const s16* __restrict__ BuT_,
    s16* __restrict__ Hout_)
{
  constexpr int K = H_;   // 1024
  constexpr int N = I_;   // 4096
  __shared__ s16 sA[128 * 64], sBg[128 * 64], sBu[128 * 64];   // 48 KiB

  const size_t e = blockIdx.z;
  const s16* A   = A_   + e * (size_t)C_ * H_;
  const s16* BgT = BgT_ + e * (size_t)I_ * H_;
  const s16* BuT = BuT_ + e * (size_t)I_ * H_;
  s16* Hout      = Hout_ + e * (size_t)C_ * I_;

  const int tid  = threadIdx.x;
  const int wave = tid >> 6, lane = tid & 63;
  const int rowA0 = blockIdx.y * 128;     // M tile
  const int rowB0 = blockIdx.x * 128;     // N tile
  const int wm = (wave >> 1) * 64, wn = (wave & 1) * 64;

  f32x4 accG[4][4], accU[4][4];
  for (int m = 0; m < 4; ++m)
    for (int n = 0; n < 4; ++n) {
      accG[m][n] = (f32x4){0.f, 0.f, 0.f, 0.f};
      accU[m][n] = (f32x4){0.f, 0.f, 0.f, 0.f};
    }

  const int srow = lane >> 3, scol = (lane & 7) * 8;   // staging lane map
  const int lr = lane & 15, lkb = (lane >> 4) * 8;     // fragment lane map

  for (int kt = 0; kt < K / 64; ++kt) {
    const int k0 = kt * 64;
    // stage A, Bg, Bu tiles: each wave 4 chunks/tile, 1KiB per gload16
    for (int i = 0; i < 4; ++i) {
      const int chunk = wave * 4 + i;          // rows 8*chunk .. 8*chunk+7
      const int r = chunk * 8 + srow;
      gload16(A   + (size_t)(rowA0 + r) * K + k0 + scol, &sA [chunk * 512]);
      gload16(BgT + (size_t)(rowB0 + r) * K + k0 + scol, &sBg[chunk * 512]);
      gload16(BuT + (size_t)(rowB0 + r) * K + k0 + scol, &sBu[chunk * 512]);
    }
    __syncthreads();   // compiler drains vmcnt before s_barrier

    for (int kk = 0; kk < 2; ++kk) {
      short8 a[4], bg[4], bu[4];
      const int lk = kk * 32 + lkb;
      for (int m = 0; m < 4; ++m)
        a[m] = *(const short8*)&sA[(wm + m * 16 + lr) * 64 + lk];
      for (int n = 0; n < 4; ++n) {
        bg[n] = *(const short8*)&sBg[(wn + n * 16 + lr) * 64 + lk];
        bu[n] = *(const short8*)&sBu[(wn + n * 16 + lr) * 64 + lk];
      }
      for (int m = 0; m < 4; ++m)
        for (int n = 0; n < 4; ++n) {
          accG[m][n] = __builtin_amdgcn_mfma_f32_16x16x32_bf16(a[m], bg[n], accG[m][n], 0, 0, 0);
          accU[m][n] = __builtin_amdgcn_mfma_f32_16x16x32_bf16(a[m], bu[n], accU[m][n], 0, 0, 0);
        }
    }
    __syncthreads();
  }

  // epilogue: silu(g)*u -> bf16.  C/D map: col = lane&15, row = (lane>>4)*4 + j
  const int lq = (lane >> 4) * 4;
  for (int m = 0; m < 4; ++m)
    for (int n = 0; n < 4; ++n) {
      const int row = rowA0 + wm + m * 16 + lq;
      const int col = rowB0 + wn + n * 16 + lr;
      s16* hp = Hout + (size_t)row * N + col;
      for (int j = 0; j < 4; ++j) {
        float g = accG[m][n][j], u = accU[m][n][j];
        float sg = 1.0f / (1.0f + __expf(-g));
        hp[(size_t)j * N] = f2bf(g * sg * u);
      }
    }
}

// ---------------------------------------------------------------------------
// gemm_down: out = h @ Wd.  expert = blockIdx.z.
// A  = h   [e][C_][I_] bf16, Bt = WdT [e][H_][I_] bf16, out fp32 [e][C_][H_]
// ---------------------------------------------------------------------------
__global__ __launch_bounds__(256, 2) void gemm_down(
    const s16* __restrict__ A_,
    const s16* __restrict__ BT_,
    float* __restrict__ Out_)
{
  constexpr int K = I_;   // 4096
  constexpr int N = H_;   // 1024
  __shared__ s16 sA[128 * 64], sB[128 * 64];   // 32 KiB

  const size_t e = blockIdx.z;
  const s16* A  = A_  + e * (size_t)C_ * I_;
  const s16* BT = BT_ + e * (size_t)H_ * I_;
  float* Out    = Out_ + e * (size_t)C_ * H_;

  const int tid  = threadIdx.x;
  const int wave = tid >> 6, lane = tid & 63;
  const int rowA0 = blockIdx.y * 128;
  const int rowB0 = blockIdx.x * 128;
  const int wm = (wave >> 1) * 64, wn = (wave & 1) * 64;

  f32x4 acc[4][4];
  for (int m = 0; m < 4; ++m)
    for (int n = 0; n < 4; ++n) acc[m][n] = (f32x4){0.f, 0.f, 0.f, 0.f};

  const int srow = lane >> 3, scol = (lane & 7) * 8;
  const int lr = lane & 15, lkb = (lane >> 4) * 8;

  for (int kt = 0; kt < K / 64; ++kt) {
    const int k0 = kt * 64;
    for (int i = 0; i < 4; ++i) {
      const int chunk = wave * 4 + i;
      const int r = chunk * 8 + srow;
      gload16(A  + (size_t)(rowA0 + r) * K + k0 + scol, &sA[chunk * 512]);
      gload16(BT + (size_t)(rowB0 + r) * K + k0 + scol, &sB[chunk * 512]);
    }
    __syncthreads();

    for (int kk = 0; kk < 2; ++kk) {
      short8 a[4], b[4];
      const int lk = kk * 32 + lkb;
      for (int m = 0; m < 4; ++m)
        a[m] = *(const short8*)&sA[(wm + m * 16 + lr) * 64 + lk];
      for (int n = 0; n < 4; ++n)
        b[n] = *(const short8*)&sB[(wn + n * 16 + lr) * 64 + lk];
      for (int m = 0; m < 4; ++m)
        for (int n = 0; n < 4; ++n)
          acc[m][n] = __builtin_amdgcn_mfma_f32_16x16x32_bf16(a[m], b[n], acc[m][n], 0, 0, 0);
    }
    __syncthreads();
  }

  const int lq = (lane >> 4) * 4;
  for (int m = 0; m < 4; ++m)
    for (int n = 0; n < 4; ++n) {
      const int row = rowA0 + wm + m * 16 + lq;
      const int col = rowB0 + wn + n * 16 + lr;
      float* op = Out + (size_t)row * N + col;
      for (int j = 0; j < 4; ++j)
        op[(size_t)j * N] = acc[m][n][j];
    }
}

// ---------------------------------------------------------------------------
extern "C" void kernel_launch(void* const* d_in, const int* in_sizes, int n_in,
                              void* d_out, int out_size, void* d_ws, size_t ws_size,
                              hipStream_t stream) {
  const float* x  = (const float*)d_in[0];
  const float* Wg = (const float*)d_in[1];
  const float* Wu = (const float*)d_in[2];
  const float* Wd = (const float*)d_in[3];
  float* out = (float*)d_out;

  const size_t szX = (size_t)C_ * H_;   // per-expert elements
  const size_t szW = (size_t)H_ * I_;
  const size_t szH = (size_t)C_ * I_;

  // full-batch workspace: xb + WgT + WuT + WdT + h (all experts) = 512 MiB
  const size_t needFull =
      2 * (E_ * szX + 3 * (size_t)E_ * szW + (size_t)E_ * szH);

  if (ws_size >= needFull) {
    // ---- batched path: 3 dispatches, expert = blockIdx.y/z ----
    s16* xb  = (s16*)d_ws;                 // E*C*H
    s16* WgT = xb  + (size_t)E_ * szX;     // E*I*H
    s16* WuT = WgT + (size_t)E_ * szW;
    s16* WdT = WuT + (size_t)E_ * szW;
    s16* hbf = WdT + (size_t)E_ * szW;     // E*C*I

    prep_kernel<<<dim3(1024, E_, 4), 256, 0, stream>>>(
        x, Wg, Wu, Wd, xb, WgT, WuT, WdT);
    gemm_gateup<<<dim3(I_ / 128, C_ / 128, E_), 256, 0, stream>>>(
        xb, WgT, WuT, hbf);
    gemm_down<<<dim3(H_ / 128, C_ / 128, E_), 256, 0, stream>>>(
        hbf, WdT, out);
  } else {
    // ---- fallback: per-expert loop (67 MiB workspace) ----
    s16* xb  = (s16*)d_ws;
    s16* WgT = xb  + szX;
    s16* WuT = WgT + szW;
    s16* WdT = WuT + szW;
    s16* hbf = WdT + szW;

    for (int e = 0; e < E_; ++e) {
      prep_kernel<<<dim3(1024, 1, 4), 256, 0, stream>>>(
          x + e * szX, Wg + e * szW, Wu + e * szW, Wd + e * szW,
          xb, WgT, WuT, WdT);
      gemm_gateup<<<dim3(I_ / 128, C_ / 128, 1), 256, 0, stream>>>(
          xb, WgT, WuT, hbf);
      gemm_down<<<dim3(H_ / 128, C_ / 128, 1), 256, 0, stream>>>(
          hbf, WdT, out + e * szX);
    }
  }
}

// Round 3
// 988.656 us; speedup vs baseline: 1.4053x; 1.1679x over previous
//
#include <hip/hip_runtime.h>
#include <hip/hip_bf16.h>
#include <stdint.h>
#include <stddef.h>

#define E_ 8
#define C_ 4096
#define H_ 1024
#define I_ 4096

typedef short s16;
typedef __attribute__((ext_vector_type(8))) short short8;   // 8 bf16 (4 VGPRs)
typedef __attribute__((ext_vector_type(4))) float f32x4;    // MFMA C/D frag
typedef __attribute__((ext_vector_type(4))) float float4v;

__device__ __forceinline__ s16 f2bf(float f) {
  union { __hip_bfloat16 h; s16 s; } u;
  u.h = __float2bfloat16(f);
  return u.s;
}

// async global->LDS, 16B per lane. LDS dest is wave-uniform base + lane*16.
__device__ __forceinline__ void gload16(const void* gsrc, void* ldst) {
  __builtin_amdgcn_global_load_lds(
      (const __attribute__((address_space(1))) void*)gsrc,
      (__attribute__((address_space(3))) void*)ldst, 16, 0, 0);
}

// ---------------------------------------------------------------------------
// prep: expert = blockIdx.y
// z=0: x fp32 -> bf16
// z=1: Wg [H][I] -> interleaved Wgu rows (gate block)   [2I][H] bf16
// z=2: Wu [H][I] -> interleaved Wgu rows (up block)
// z=3: Wd [I][H] -> WdT [H][I] bf16
// Interleave: real col i -> row (i&~15)*2 + (i&15) (+16 for up), so a
// standard GEMM on Wgu puts gate/up for the same i in adjacent n-fragments.
// ---------------------------------------------------------------------------
__global__ __launch_bounds__(256) void prep_kernel(
    const float* __restrict__ x, const float* __restrict__ Wg,
    const float* __restrict__ Wu, const float* __restrict__ Wd,
    s16* __restrict__ xb, s16* __restrict__ Wgu, s16* __restrict__ WdT)
{
  __shared__ float tile[64][65];
  const int t = threadIdx.x;
  const int z = blockIdx.z;
  const size_t e = blockIdx.y;

  if (z == 0) {
    size_t base = e * (size_t)C_ * H_ + ((size_t)blockIdx.x * 256 + t) * 16;
    for (int j = 0; j < 16; j += 8) {
      float4v v0 = *(const float4v*)(x + base + j);
      float4v v1 = *(const float4v*)(x + base + j + 4);
      s16 o[8];
      o[0] = f2bf(v0[0]); o[1] = f2bf(v0[1]); o[2] = f2bf(v0[2]); o[3] = f2bf(v0[3]);
      o[4] = f2bf(v1[0]); o[5] = f2bf(v1[1]); o[6] = f2bf(v1[2]); o[7] = f2bf(v1[3]);
      *(short8*)(xb + base + j) = *(short8*)o;
    }
    return;
  }

  const float* src; int Cc;
  if (z == 1)      { src = Wg + e * (size_t)H_ * I_; Cc = I_; }
  else if (z == 2) { src = Wu + e * (size_t)H_ * I_; Cc = I_; }
  else             { src = Wd + e * (size_t)H_ * I_; Cc = H_; }

  const int tpr  = Cc >> 6;
  const int trow = blockIdx.x / tpr;
  const int tcol = blockIdx.x % tpr;

  const int c = t & 63, rq = t >> 6;
  for (int i = 0; i < 16; ++i) {
    int r = rq * 16 + i;
    tile[r][c] = src[(size_t)(trow * 64 + r) * Cc + tcol * 64 + c];
  }
  __syncthreads();

  const int ro = t >> 2, cb = (t & 3) * 16;
  s16 o[16];
  for (int j = 0; j < 16; ++j) o[j] = f2bf(tile[cb + j][ro]);

  const int i0 = tcol * 64 + ro;   // transposed row index
  s16* op;
  if (z == 3) {
    op = WdT + e * (size_t)H_ * I_ + (size_t)i0 * I_ + trow * 64 + cb;
  } else {
    int grow = ((i0 & ~15) << 1) + (i0 & 15) + ((z == 2) ? 16 : 0);
    op = Wgu + e * (size_t)2 * I_ * H_ + (size_t)grow * H_ + trow * 64 + cb;
  }
  *(short8*)op       = *(short8*)&o[0];
  *(short8*)(op + 8) = *(short8*)&o[8];
}

// ---------------------------------------------------------------------------
// 256x256-tile 8-phase GEMM (m201-style template, plain HIP).
// A [e][C_][K] bf16 (K contiguous), B [e][NB][K] bf16 (K contiguous).
// GATEUP: K=1024, NB=8192 (interleaved Wgu), out = silu(g)*u -> bf16 [e][C_][I_]
// !GATEUP: K=4096, NB=1024 (WdT),             out = fp32 [e][C_][H_]
// 512 thr = 8 waves (2M x 4N); per-wave 128x64; LDS 128 KiB dbuf.
// T2: LDS linear (gload_lds), source col pre-swizzled with col^=(row&7)<<3;
// ds_read applies the same XOR.
// T4: single vmcnt(4) per K-tile (phases 4/8); prefetch ledger in comments.
// ---------------------------------------------------------------------------
#define LDAF(B, MH, M, CX) \
  (*(const short8*)(shm + (B)*16384 + ((wm + (MH)*64 + (M)*16 + lr) << 6) + (CX)))
#define LDBF(B, N, CX) \
  (*(const short8*)(shm + 32768 + (B)*16384 + ((wn + (N)*16 + lr) << 6) + (CX)))

#define MFMA16(MH, A0, A1, A2, A3)                                                            \
  acc[(MH)*4+0][0] = __builtin_amdgcn_mfma_f32_16x16x32_bf16(A0, bf[0], acc[(MH)*4+0][0],0,0,0); \
  acc[(MH)*4+0][1] = __builtin_amdgcn_mfma_f32_16x16x32_bf16(A0, bf[1], acc[(MH)*4+0][1],0,0,0); \
  acc[(MH)*4+0][2] = __builtin_amdgcn_mfma_f32_16x16x32_bf16(A0, bf[2], acc[(MH)*4+0][2],0,0,0); \
  acc[(MH)*4+0][3] = __builtin_amdgcn_mfma_f32_16x16x32_bf16(A0, bf[3], acc[(MH)*4+0][3],0,0,0); \
  acc[(MH)*4+1][0] = __builtin_amdgcn_mfma_f32_16x16x32_bf16(A1, bf[0], acc[(MH)*4+1][0],0,0,0); \
  acc[(MH)*4+1][1] = __builtin_amdgcn_mfma_f32_16x16x32_bf16(A1, bf[1], acc[(MH)*4+1][1],0,0,0); \
  acc[(MH)*4+1][2] = __builtin_amdgcn_mfma_f32_16x16x32_bf16(A1, bf[2], acc[(MH)*4+1][2],0,0,0); \
  acc[(MH)*4+1][3] = __builtin_amdgcn_mfma_f32_16x16x32_bf16(A1, bf[3], acc[(MH)*4+1][3],0,0,0); \
  acc[(MH)*4+2][0] = __builtin_amdgcn_mfma_f32_16x16x32_bf16(A2, bf[0], acc[(MH)*4+2][0],0,0,0); \
  acc[(MH)*4+2][1] = __builtin_amdgcn_mfma_f32_16x16x32_bf16(A2, bf[1], acc[(MH)*4+2][1],0,0,0); \
  acc[(MH)*4+2][2] = __builtin_amdgcn_mfma_f32_16x16x32_bf16(A2, bf[2], acc[(MH)*4+2][2],0,0,0); \
  acc[(MH)*4+2][3] = __builtin_amdgcn_mfma_f32_16x16x32_bf16(A2, bf[3], acc[(MH)*4+2][3],0,0,0); \
  acc[(MH)*4+3][0] = __builtin_amdgcn_mfma_f32_16x16x32_bf16(A3, bf[0], acc[(MH)*4+3][0],0,0,0); \
  acc[(MH)*4+3][1] = __builtin_amdgcn_mfma_f32_16x16x32_bf16(A3, bf[1], acc[(MH)*4+3][1],0,0,0); \
  acc[(MH)*4+3][2] = __builtin_amdgcn_mfma_f32_16x16x32_bf16(A3, bf[2], acc[(MH)*4+3][2],0,0,0); \
  acc[(MH)*4+3][3] = __builtin_amdgcn_mfma_f32_16x16x32_bf16(A3, bf[3], acc[(MH)*4+3][3],0,0,0);

#define VMW4 asm volatile("s_waitcnt vmcnt(4)" ::: "memory");

#define PHASE(B, MH, CX, RDB, STMT, WV)                                      \
  {                                                                          \
    short8 af0 = LDAF(B, MH, 0, CX);                                         \
    short8 af1 = LDAF(B, MH, 1, CX);                                         \
    short8 af2 = LDAF(B, MH, 2, CX);                                         \
    short8 af3 = LDAF(B, MH, 3, CX);                                         \
    if (RDB) {                                                               \
      bf[0] = LDBF(B, 0, CX); bf[1] = LDBF(B, 1, CX);                        \
      bf[2] = LDBF(B, 2, CX); bf[3] = LDBF(B, 3, CX);                        \
    }                                                                        \
    STMT                                                                     \
    __builtin_amdgcn_sched_barrier(0);                                       \
    __builtin_amdgcn_s_barrier();                                            \
    asm volatile("s_waitcnt lgkmcnt(0)" ::: "memory");                       \
    __builtin_amdgcn_sched_barrier(0);                                       \
    __builtin_amdgcn_s_setprio(1);                                           \
    MFMA16(MH, af0, af1, af2, af3)                                           \
    __builtin_amdgcn_s_setprio(0);                                           \
    __builtin_amdgcn_sched_barrier(0);                                       \
    WV                                                                       \
    __builtin_amdgcn_s_barrier();                                            \
  }

template<bool GATEUP>
__global__ __launch_bounds__(512, 2) void gemm256(
    const s16* __restrict__ Abase, const s16* __restrict__ Bbase,
    s16* __restrict__ HOut, float* __restrict__ FOut)
{
  constexpr int K  = GATEUP ? H_ : I_;
  constexpr int NB = GATEUP ? 2 * I_ : H_;
  constexpr int NT = K / 64;                 // K-tiles
  constexpr int TN = NB / 256;
  constexpr int TM = C_ / 256;
  constexpr int NWG = TM * TN;               // % 8 == 0 for both

  __shared__ s16 shm[65536];                 // 128 KiB: A dbuf 64K | B dbuf 64K

  const int tid  = threadIdx.x;
  const int wave = tid >> 6, lane = tid & 63;
  const int e    = blockIdx.z;

  // T1: XCD-aware bijective swizzle
  const int bid = blockIdx.x;
  const int swz = (bid & 7) * (NWG / 8) + (bid >> 3);
  const int bm  = swz / TN, bn = swz % TN;

  const s16* A = Abase + (size_t)e * C_ * K + (size_t)bm * 256 * K;
  const s16* B = Bbase + (size_t)e * NB * K + (size_t)bn * 256 * K;

  const int wm  = (wave >> 2) * 128;
  const int wn  = (wave & 3) * 64;
  const int lr  = lane & 15;
  const int lkb = (lane >> 4) * 8;
  const int xr  = (lr & 7) << 3;             // T2 read-side XOR
  const int cx0 = lkb ^ xr;                  // kk=0 col (elements)
  const int cx1 = (32 + lkb) ^ xr;           // kk=1

  // staging: thread tid covers row (h*128 + l*64 + tid>>3), swizzled col
  const int srow = tid >> 3;
  const int scol = ((tid & 7) ^ (srow & 7)) * 8;   // T2 write-side (source) XOR
  const size_t stoff = (size_t)srow * K + scol;
  const int sdst = wave * 512;               // wave-uniform LDS slot (elements)

  auto stageA = [&](int kt, int b) {
    #pragma unroll
    for (int h = 0; h < 2; ++h)
      #pragma unroll
      for (int l = 0; l < 2; ++l)
        gload16(A + (size_t)(h * 128 + l * 64) * K + (size_t)kt * 64 + stoff,
                shm + b * 16384 + h * 8192 + l * 4096 + sdst);
  };
  auto stageB = [&](int kt, int b) {
    #pragma unroll
    for (int h = 0; h < 2; ++h)
      #pragma unroll
      for (int l = 0; l < 2; ++l)
        gload16(B + (size_t)(h * 128 + l * 64) * K + (size_t)kt * 64 + stoff,
                shm + 32768 + b * 16384 + h * 8192 + l * 4096 + sdst);
  };

  f32x4 acc[8][4];
  #pragma unroll
  for (int m = 0; m < 8; ++m)
    #pragma unroll
    for (int n = 0; n < 4; ++n) acc[m][n] = (f32x4){0.f, 0.f, 0.f, 0.f};

  // prologue: tile0 (buf0) fully + tile1.B (buf1); leave t1.B in flight
  stageB(0, 0);
  stageA(0, 0);
  stageB(1, 1);
  asm volatile("s_waitcnt vmcnt(4)" ::: "memory");
  __builtin_amdgcn_sched_barrier(0);
  __builtin_amdgcn_s_barrier();

  short8 bf[4];
  // ledger (steady state, per iteration): issue t1.A(ph1) t2.B(ph4) t2.A(ph5)
  // t3.B(ph8); vmcnt(4) at ph4 -> t1 complete before ph5 reads buf1;
  // vmcnt(4) at ph8 -> t2 complete before next ph1 reads buf0.
  // Region safety: B halves free after ph3/ph7 barrier; A halves after ph4/ph8.
  for (int i = 0; i < NT / 2; ++i) {
    const int t1 = 2 * i + 1;
    const int t2 = (2 * i + 2 < NT) ? (2 * i + 2) : (NT - 1);
    const int t3 = (2 * i + 3 < NT) ? (2 * i + 3) : (NT - 1);
    PHASE(0, 0, cx0, 1, { stageA(t1, 1); }, )
    PHASE(0, 1, cx0, 0, {}, )
    PHASE(0, 0, cx1, 1, {}, )
    PHASE(0, 1, cx1, 0, { stageB(t2, 0); }, VMW4)
    PHASE(1, 0, cx0, 1, { stageA(t2, 0); }, )
    PHASE(1, 1, cx0, 0, {}, )
    PHASE(1, 0, cx1, 1, {}, )
    PHASE(1, 1, cx1, 0, { stageB(t3, 1); }, VMW4)
  }

  // epilogue
  const int lq = (lane >> 4) * 4;
  if constexpr (GATEUP) {
    s16* Hp = HOut + (size_t)e * C_ * I_;
    const int ibase = bn * 128 + (wn >> 1);
    #pragma unroll
    for (int m = 0; m < 8; ++m) {
      const int row = bm * 256 + wm + m * 16 + lq;
      #pragma unroll
      for (int p = 0; p < 2; ++p) {
        const int col = ibase + p * 16 + lr;
        s16* hp = Hp + (size_t)row * I_ + col;
        #pragma unroll
        for (int j = 0; j < 4; ++j) {
          float g = acc[m][2 * p][j], u = acc[m][2 * p + 1][j];
          float sg = 1.0f / (1.0f + __expf(-g));
          hp[(size_t)j * I_] = f2bf(g * sg * u);
        }
      }
    }
  } else {
    float* Op = FOut + (size_t)e * C_ * H_;
    #pragma unroll
    for (int m = 0; m < 8; ++m) {
      const int row = bm * 256 + wm + m * 16 + lq;
      #pragma unroll
      for (int n = 0; n < 4; ++n) {
        const int col = bn * 256 + wn + n * 16 + lr;
        #pragma unroll
        for (int j = 0; j < 4; ++j)
          Op[(size_t)(row + j) * H_ + col] = acc[m][n][j];
      }
    }
  }
}

// ---------------------------------------------------------------------------
extern "C" void kernel_launch(void* const* d_in, const int* in_sizes, int n_in,
                              void* d_out, int out_size, void* d_ws, size_t ws_size,
                              hipStream_t stream) {
  const float* x  = (const float*)d_in[0];
  const float* Wg = (const float*)d_in[1];
  const float* Wu = (const float*)d_in[2];
  const float* Wd = (const float*)d_in[3];
  float* out = (float*)d_out;

  const size_t szX  = (size_t)C_ * H_;
  const size_t szGU = (size_t)2 * I_ * H_;
  const size_t szWd = (size_t)H_ * I_;
  const size_t szH  = (size_t)C_ * I_;

  const size_t needFull = 2 * E_ * (szX + szGU + szWd + szH);   // 512 MiB

  if (ws_size >= needFull) {
    s16* xb  = (s16*)d_ws;                  // [E][C][H]
    s16* Wgu = xb  + E_ * szX;              // [E][2I][H] interleaved
    s16* WdT = Wgu + E_ * szGU;             // [E][H][I]
    s16* hbf = WdT + E_ * szWd;             // [E][C][I]

    prep_kernel<<<dim3(1024, E_, 4), 256, 0, stream>>>(
        x, Wg, Wu, Wd, xb, Wgu, WdT);
    gemm256<true><<<dim3((C_/256)*(2*I_/256), 1, E_), 512, 0, stream>>>(
        xb, Wgu, hbf, nullptr);
    gemm256<false><<<dim3((C_/256)*(H_/256), 1, E_), 512, 0, stream>>>(
        hbf, WdT, nullptr, out);
  } else {
    // per-expert fallback (67 MiB workspace), same kernels with gridZ=1
    s16* xb  = (s16*)d_ws;
    s16* Wgu = xb  + szX;
    s16* WdT = Wgu + szGU;
    s16* hbf = WdT + szWd;

    for (int e = 0; e < E_; ++e) {
      prep_kernel<<<dim3(1024, 1, 4), 256, 0, stream>>>(
          x + e * szX, Wg + e * szWd, Wu + e * szWd, Wd + e * szWd,
          xb, Wgu, WdT);
      gemm256<true><<<dim3((C_/256)*(2*I_/256), 1, 1), 512, 0, stream>>>(
          xb, Wgu, hbf, nullptr);
      gemm256<false><<<dim3((C_/256)*(H_/256), 1, 1), 512, 0, stream>>>(
          hbf, WdT, nullptr, out + e * szX);
    }
  }
}

// Round 4
// 965.378 us; speedup vs baseline: 1.4392x; 1.0241x over previous
//
#include <hip/hip_runtime.h>
#include <hip/hip_bf16.h>
#include <stdint.h>
#include <stddef.h>

#define E_ 8
#define C_ 4096
#define H_ 1024
#define I_ 4096

typedef short s16;
typedef __attribute__((ext_vector_type(8))) short short8;   // 8 bf16 (4 VGPRs)
typedef __attribute__((ext_vector_type(4))) float f32x4;    // MFMA C/D frag
typedef __attribute__((ext_vector_type(4))) float float4v;

__device__ __forceinline__ s16 f2bf(float f) {
  union { __hip_bfloat16 h; s16 s; } u;
  u.h = __float2bfloat16(f);
  return u.s;
}

// async global->LDS, 16B per lane. LDS dest is wave-uniform base + lane*16.
__device__ __forceinline__ void gload16(const void* gsrc, void* ldst) {
  __builtin_amdgcn_global_load_lds(
      (const __attribute__((address_space(1))) void*)gsrc,
      (__attribute__((address_space(3))) void*)ldst, 16, 0, 0);
}

// ---------------------------------------------------------------------------
// prep: expert = blockIdx.y
// z=0: x fp32 -> bf16
// z=1: Wg [H][I] -> interleaved Wgu rows (gate block)   [2I][H] bf16
// z=2: Wu [H][I] -> interleaved Wgu rows (up block)
// z=3: Wd [I][H] -> WdT [H][I] bf16
// Interleave: real col i -> row (i&~15)*2 + (i&15) (+16 for up), so a
// standard GEMM on Wgu puts gate/up for the same i in adjacent n-fragments.
// ---------------------------------------------------------------------------
__global__ __launch_bounds__(256) void prep_kernel(
    const float* __restrict__ x, const float* __restrict__ Wg,
    const float* __restrict__ Wu, const float* __restrict__ Wd,
    s16* __restrict__ xb, s16* __restrict__ Wgu, s16* __restrict__ WdT)
{
  __shared__ float tile[64][65];
  const int t = threadIdx.x;
  const int z = blockIdx.z;
  const size_t e = blockIdx.y;

  if (z == 0) {
    size_t base = e * (size_t)C_ * H_ + ((size_t)blockIdx.x * 256 + t) * 16;
    for (int j = 0; j < 16; j += 8) {
      float4v v0 = *(const float4v*)(x + base + j);
      float4v v1 = *(const float4v*)(x + base + j + 4);
      s16 o[8];
      o[0] = f2bf(v0[0]); o[1] = f2bf(v0[1]); o[2] = f2bf(v0[2]); o[3] = f2bf(v0[3]);
      o[4] = f2bf(v1[0]); o[5] = f2bf(v1[1]); o[6] = f2bf(v1[2]); o[7] = f2bf(v1[3]);
      *(short8*)(xb + base + j) = *(short8*)o;
    }
    return;
  }

  const float* src; int Cc;
  if (z == 1)      { src = Wg + e * (size_t)H_ * I_; Cc = I_; }
  else if (z == 2) { src = Wu + e * (size_t)H_ * I_; Cc = I_; }
  else             { src = Wd + e * (size_t)H_ * I_; Cc = H_; }

  const int tpr  = Cc >> 6;
  const int trow = blockIdx.x / tpr;
  const int tcol = blockIdx.x % tpr;

  const int c = t & 63, rq = t >> 6;
  for (int i = 0; i < 16; ++i) {
    int r = rq * 16 + i;
    tile[r][c] = src[(size_t)(trow * 64 + r) * Cc + tcol * 64 + c];
  }
  __syncthreads();

  const int ro = t >> 2, cb = (t & 3) * 16;
  s16 o[16];
  for (int j = 0; j < 16; ++j) o[j] = f2bf(tile[cb + j][ro]);

  const int i0 = tcol * 64 + ro;   // transposed row index
  s16* op;
  if (z == 3) {
    op = WdT + e * (size_t)H_ * I_ + (size_t)i0 * I_ + trow * 64 + cb;
  } else {
    int grow = ((i0 & ~15) << 1) + (i0 & 15) + ((z == 2) ? 16 : 0);
    op = Wgu + e * (size_t)2 * I_ * H_ + (size_t)grow * H_ + trow * 64 + cb;
  }
  *(short8*)op       = *(short8*)&o[0];
  *(short8*)(op + 8) = *(short8*)&o[8];
}

// ---------------------------------------------------------------------------
// 256x256-tile 8-phase GEMM (m201-style template, plain HIP).
// A [e][C_][K] bf16 (K contiguous), B [e][NB][K] bf16 (K contiguous).
// GATEUP: K=1024, NB=8192 (interleaved Wgu), out = silu(g)*u -> bf16 [e][C_][I_]
// !GATEUP: K=4096, NB=1024 (WdT),             out = fp32 [e][C_][H_]
// 512 thr = 8 waves (2M x 4N); per-wave 128x64; LDS 128 KiB dbuf.
// T2: LDS linear (gload_lds), source col pre-swizzled with col^=(row&7)<<3;
// ds_read applies the same XOR.
// T4: single vmcnt(4) per K-tile (phases 4/8); prefetch ledger in comments.
// ---------------------------------------------------------------------------
#define LDAF(B, MH, M, CX) \
  (*(const short8*)(shm + (B)*16384 + ((wm + (MH)*64 + (M)*16 + lr) << 6) + (CX)))
#define LDBF(B, N, CX) \
  (*(const short8*)(shm + 32768 + (B)*16384 + ((wn + (N)*16 + lr) << 6) + (CX)))

#define MFMA16(MH, A0, A1, A2, A3)                                                            \
  acc[(MH)*4+0][0] = __builtin_amdgcn_mfma_f32_16x16x32_bf16(A0, bf[0], acc[(MH)*4+0][0],0,0,0); \
  acc[(MH)*4+0][1] = __builtin_amdgcn_mfma_f32_16x16x32_bf16(A0, bf[1], acc[(MH)*4+0][1],0,0,0); \
  acc[(MH)*4+0][2] = __builtin_amdgcn_mfma_f32_16x16x32_bf16(A0, bf[2], acc[(MH)*4+0][2],0,0,0); \
  acc[(MH)*4+0][3] = __builtin_amdgcn_mfma_f32_16x16x32_bf16(A0, bf[3], acc[(MH)*4+0][3],0,0,0); \
  acc[(MH)*4+1][0] = __builtin_amdgcn_mfma_f32_16x16x32_bf16(A1, bf[0], acc[(MH)*4+1][0],0,0,0); \
  acc[(MH)*4+1][1] = __builtin_amdgcn_mfma_f32_16x16x32_bf16(A1, bf[1], acc[(MH)*4+1][1],0,0,0); \
  acc[(MH)*4+1][2] = __builtin_amdgcn_mfma_f32_16x16x32_bf16(A1, bf[2], acc[(MH)*4+1][2],0,0,0); \
  acc[(MH)*4+1][3] = __builtin_amdgcn_mfma_f32_16x16x32_bf16(A1, bf[3], acc[(MH)*4+1][3],0,0,0); \
  acc[(MH)*4+2][0] = __builtin_amdgcn_mfma_f32_16x16x32_bf16(A2, bf[0], acc[(MH)*4+2][0],0,0,0); \
  acc[(MH)*4+2][1] = __builtin_amdgcn_mfma_f32_16x16x32_bf16(A2, bf[1], acc[(MH)*4+2][1],0,0,0); \
  acc[(MH)*4+2][2] = __builtin_amdgcn_mfma_f32_16x16x32_bf16(A2, bf[2], acc[(MH)*4+2][2],0,0,0); \
  acc[(MH)*4+2][3] = __builtin_amdgcn_mfma_f32_16x16x32_bf16(A2, bf[3], acc[(MH)*4+2][3],0,0,0); \
  acc[(MH)*4+3][0] = __builtin_amdgcn_mfma_f32_16x16x32_bf16(A3, bf[0], acc[(MH)*4+3][0],0,0,0); \
  acc[(MH)*4+3][1] = __builtin_amdgcn_mfma_f32_16x16x32_bf16(A3, bf[1], acc[(MH)*4+3][1],0,0,0); \
  acc[(MH)*4+3][2] = __builtin_amdgcn_mfma_f32_16x16x32_bf16(A3, bf[2], acc[(MH)*4+3][2],0,0,0); \
  acc[(MH)*4+3][3] = __builtin_amdgcn_mfma_f32_16x16x32_bf16(A3, bf[3], acc[(MH)*4+3][3],0,0,0);

#define VMW4 asm volatile("s_waitcnt vmcnt(4)" ::: "memory");

#define PHASE(B, MH, CX, RDB, STMT, WV)                                      \
  {                                                                          \
    short8 af0 = LDAF(B, MH, 0, CX);                                         \
    short8 af1 = LDAF(B, MH, 1, CX);                                         \
    short8 af2 = LDAF(B, MH, 2, CX);                                         \
    short8 af3 = LDAF(B, MH, 3, CX);                                         \
    if (RDB) {                                                               \
      bf[0] = LDBF(B, 0, CX); bf[1] = LDBF(B, 1, CX);                        \
      bf[2] = LDBF(B, 2, CX); bf[3] = LDBF(B, 3, CX);                        \
    }                                                                        \
    STMT                                                                     \
    __builtin_amdgcn_sched_barrier(0);                                       \
    __builtin_amdgcn_s_barrier();                                            \
    asm volatile("s_waitcnt lgkmcnt(0)" ::: "memory");                       \
    __builtin_amdgcn_sched_barrier(0);                                       \
    __builtin_amdgcn_s_setprio(1);                                           \
    MFMA16(MH, af0, af1, af2, af3)                                           \
    __builtin_amdgcn_s_setprio(0);                                           \
    __builtin_amdgcn_sched_barrier(0);                                       \
    WV                                                                       \
    __builtin_amdgcn_s_barrier();                                            \
  }

template<bool GATEUP>
__global__ __launch_bounds__(512, 2) void gemm256(
    const s16* __restrict__ Abase, const s16* __restrict__ Bbase,
    s16* __restrict__ HOut, float* __restrict__ FOut)
{
  constexpr int K  = GATEUP ? H_ : I_;
  constexpr int NB = GATEUP ? 2 * I_ : H_;
  constexpr int NT = K / 64;                 // K-tiles
  constexpr int TN = NB / 256;
  constexpr int TM = C_ / 256;
  constexpr int NWG = TM * TN;               // % 8 == 0 for both

  __shared__ s16 shm[65536];                 // 128 KiB: A dbuf 64K | B dbuf 64K

  const int tid  = threadIdx.x;
  const int wave = tid >> 6, lane = tid & 63;
  const int e    = blockIdx.z;

  // Block->tile mapping. gridX % 8 == 0, so (bid & 7) is XCD-stable across z.
  const int bid = blockIdx.x;
  int bm, bn;
  if constexpr (GATEUP) {
    // Fetch-optimal per-XCD partition: each XCD owns an 8bn x 8bm sub-grid
    // (cg = xcd&3 picks bn octet, rg = xcd>>2 picks bm octet), bn-inner order.
    // Per-XCD live set: B 4 MB (re-touched every block -> L2-resident) +
    // A ~2 MB. Cuts per-expert far-fetch ~135 MB -> ~64 MB.
    const int xcd = bid & 7;
    const int idx = bid >> 3;                // 0..63
    bn = (xcd & 3) * 8 + (idx & 7);
    bm = (xcd >> 2) * 8 + (idx >> 3);
  } else {
    // down: panels too large for L2 residency at 1 block/CU; keep the plain
    // bijective XCD swizzle (already at template-ceiling efficiency).
    const int swz = (bid & 7) * (NWG / 8) + (bid >> 3);
    bm = swz / TN; bn = swz % TN;
  }

  const s16* A = Abase + (size_t)e * C_ * K + (size_t)bm * 256 * K;
  const s16* B = Bbase + (size_t)e * NB * K + (size_t)bn * 256 * K;

  const int wm  = (wave >> 2) * 128;
  const int wn  = (wave & 3) * 64;
  const int lr  = lane & 15;
  const int lkb = (lane >> 4) * 8;
  const int xr  = (lr & 7) << 3;             // T2 read-side XOR
  const int cx0 = lkb ^ xr;                  // kk=0 col (elements)
  const int cx1 = (32 + lkb) ^ xr;           // kk=1

  // staging: thread tid covers row (h*128 + l*64 + tid>>3), swizzled col
  const int srow = tid >> 3;
  const int scol = ((tid & 7) ^ (srow & 7)) * 8;   // T2 write-side (source) XOR
  const size_t stoff = (size_t)srow * K + scol;
  const int sdst = wave * 512;               // wave-uniform LDS slot (elements)

  auto stageA = [&](int kt, int b) {
    #pragma unroll
    for (int h = 0; h < 2; ++h)
      #pragma unroll
      for (int l = 0; l < 2; ++l)
        gload16(A + (size_t)(h * 128 + l * 64) * K + (size_t)kt * 64 + stoff,
                shm + b * 16384 + h * 8192 + l * 4096 + sdst);
  };
  auto stageB = [&](int kt, int b) {
    #pragma unroll
    for (int h = 0; h < 2; ++h)
      #pragma unroll
      for (int l = 0; l < 2; ++l)
        gload16(B + (size_t)(h * 128 + l * 64) * K + (size_t)kt * 64 + stoff,
                shm + 32768 + b * 16384 + h * 8192 + l * 4096 + sdst);
  };

  f32x4 acc[8][4];
  #pragma unroll
  for (int m = 0; m < 8; ++m)
    #pragma unroll
    for (int n = 0; n < 4; ++n) acc[m][n] = (f32x4){0.f, 0.f, 0.f, 0.f};

  // prologue: tile0 (buf0) fully + tile1.B (buf1); leave t1.B in flight
  stageB(0, 0);
  stageA(0, 0);
  stageB(1, 1);
  asm volatile("s_waitcnt vmcnt(4)" ::: "memory");
  __builtin_amdgcn_sched_barrier(0);
  __builtin_amdgcn_s_barrier();

  short8 bf[4];
  // ledger (steady state, per iteration): issue t1.A(ph1) t2.B(ph4) t2.A(ph5)
  // t3.B(ph8); vmcnt(4) at ph4 -> t1 complete before ph5 reads buf1;
  // vmcnt(4) at ph8 -> t2 complete before next ph1 reads buf0.
  // Region safety: B halves free after ph3/ph7 barrier; A halves after ph4/ph8.
  for (int i = 0; i < NT / 2; ++i) {
    const int t1 = 2 * i + 1;
    const int t2 = (2 * i + 2 < NT) ? (2 * i + 2) : (NT - 1);
    const int t3 = (2 * i + 3 < NT) ? (2 * i + 3) : (NT - 1);
    PHASE(0, 0, cx0, 1, { stageA(t1, 1); }, )
    PHASE(0, 1, cx0, 0, {}, )
    PHASE(0, 0, cx1, 1, {}, )
    PHASE(0, 1, cx1, 0, { stageB(t2, 0); }, VMW4)
    PHASE(1, 0, cx0, 1, { stageA(t2, 0); }, )
    PHASE(1, 1, cx0, 0, {}, )
    PHASE(1, 0, cx1, 1, {}, )
    PHASE(1, 1, cx1, 0, { stageB(t3, 1); }, VMW4)
  }

  // epilogue
  const int lq = (lane >> 4) * 4;
  if constexpr (GATEUP) {
    s16* Hp = HOut + (size_t)e * C_ * I_;
    const int ibase = bn * 128 + (wn >> 1);
    #pragma unroll
    for (int m = 0; m < 8; ++m) {
      const int row = bm * 256 + wm + m * 16 + lq;
      #pragma unroll
      for (int p = 0; p < 2; ++p) {
        const int col = ibase + p * 16 + lr;
        s16* hp = Hp + (size_t)row * I_ + col;
        #pragma unroll
        for (int j = 0; j < 4; ++j) {
          float g = acc[m][2 * p][j], u = acc[m][2 * p + 1][j];
          float sg = 1.0f / (1.0f + __expf(-g));
          hp[(size_t)j * I_] = f2bf(g * sg * u);
        }
      }
    }
  } else {
    float* Op = FOut + (size_t)e * C_ * H_;
    #pragma unroll
    for (int m = 0; m < 8; ++m) {
      const int row = bm * 256 + wm + m * 16 + lq;
      #pragma unroll
      for (int n = 0; n < 4; ++n) {
        const int col = bn * 256 + wn + n * 16 + lr;
        #pragma unroll
        for (int j = 0; j < 4; ++j)
          Op[(size_t)(row + j) * H_ + col] = acc[m][n][j];
      }
    }
  }
}

// ---------------------------------------------------------------------------
extern "C" void kernel_launch(void* const* d_in, const int* in_sizes, int n_in,
                              void* d_out, int out_size, void* d_ws, size_t ws_size,
                              hipStream_t stream) {
  const float* x  = (const float*)d_in[0];
  const float* Wg = (const float*)d_in[1];
  const float* Wu = (const float*)d_in[2];
  const float* Wd = (const float*)d_in[3];
  float* out = (float*)d_out;

  const size_t szX  = (size_t)C_ * H_;
  const size_t szGU = (size_t)2 * I_ * H_;
  const size_t szWd = (size_t)H_ * I_;
  const size_t szH  = (size_t)C_ * I_;

  const size_t needFull = 2 * E_ * (szX + szGU + szWd + szH);   // 512 MiB

  if (ws_size >= needFull) {
    s16* xb  = (s16*)d_ws;                  // [E][C][H]
    s16* Wgu = xb  + E_ * szX;              // [E][2I][H] interleaved
    s16* WdT = Wgu + E_ * szGU;             // [E][H][I]
    s16* hbf = WdT + E_ * szWd;             // [E][C][I]

    prep_kernel<<<dim3(1024, E_, 4), 256, 0, stream>>>(
        x, Wg, Wu, Wd, xb, Wgu, WdT);
    gemm256<true><<<dim3((C_/256)*(2*I_/256), 1, E_), 512, 0, stream>>>(
        xb, Wgu, hbf, nullptr);
    gemm256<false><<<dim3((C_/256)*(H_/256), 1, E_), 512, 0, stream>>>(
        hbf, WdT, nullptr, out);
  } else {
    // per-expert fallback (67 MiB workspace), same kernels with gridZ=1
    s16* xb  = (s16*)d_ws;
    s16* Wgu = xb  + szX;
    s16* WdT = Wgu + szGU;
    s16* hbf = WdT + szWd;

    for (int e = 0; e < E_; ++e) {
      prep_kernel<<<dim3(1024, 1, 4), 256, 0, stream>>>(
          x + e * szX, Wg + e * szWd, Wu + e * szWd, Wd + e * szWd,
          xb, Wgu, WdT);
      gemm256<true><<<dim3((C_/256)*(2*I_/256), 1, 1), 512, 0, stream>>>(
          xb, Wgu, hbf, nullptr);
      gemm256<false><<<dim3((C_/256)*(H_/256), 1, 1), 512, 0, stream>>>(
          hbf, WdT, nullptr, out + e * szX);
    }
  }
}